// Round 1
// baseline (487.035 us; speedup 1.0000x reference)
//
#include <hip/hip_runtime.h>
#include <hip/hip_bf16.h>

typedef __attribute__((ext_vector_type(8))) __bf16 bf16x8;
typedef __attribute__((ext_vector_type(4))) float  f32x4;

#define T_SEQ 256
#define F_IN  18
#define HID   64
#define NB    16
#define NO    15

static __device__ __forceinline__ float sigm(float x) {
    return 1.0f / (1.0f + __expf(-x));
}
static __device__ __forceinline__ float tanhf_fast(float x) {
    // 1 - 2/(e^{2x}+1); saturates correctly for |x| large (inf -> 1, 0 -> -1)
    float e = __expf(2.0f * x);
    return 1.0f - 2.0f / (e + 1.0f);
}

// Grid: 256 blocks (16 batches each), 512 threads = 8 waves.
// Wave w owns output-row tiles T = 2w, 2w+1 of the permuted gate matrix
// (rows p = 4*u + g, u = hidden unit, g = gate i/f/g/o), i.e. units 8w..8w+7.
// Per lane: bb = l&15 (batch), q = l>>4 (k-group). After MFMA, C reg r holds
// gate g=r for unit u = 8w + 4tt + q, batch bb -> cell update is lane-local.
__global__ __launch_bounds__(512, 2) void lstm_fused(
    const float* __restrict__ X,
    const float* __restrict__ Wih,
    const float* __restrict__ Whh,
    const float* __restrict__ bih,
    const float* __restrict__ bhh,
    const float* __restrict__ Wcls,
    const float* __restrict__ bcls,
    float* __restrict__ out)
{
    const int tid = threadIdx.x;
    const int l   = tid & 63;
    const int w   = tid >> 6;
    const int q   = l >> 4;
    const int bb  = l & 15;
    const int b0  = blockIdx.x * NB;

    // h double-buffer in B-fragment-ready layout: [dbuf][hi/lo][u>>3][b][u&7]
    __shared__ __align__(16) __bf16 hbuf[2][2][8][16][8];
    __shared__ float h32[NB][HID];

    {   // zero initial h (t=0 reads hbuf[0])
        __bf16* hz = &hbuf[0][0][0][0][0];
        for (int i = tid; i < 2 * 8 * 16 * 8; i += 512) hz[i] = (__bf16)0.0f;
    }

    // ---- constant A-fragments (weights), split hi/lo bf16, live whole kernel ----
    bf16x8 whh_hi[2][2], whh_lo[2][2];
    bf16x8 wih_hi[2],    wih_lo[2];
    float  bias[2][4];
    float  cst[2] = {0.0f, 0.0f};

#pragma unroll
    for (int tt = 0; tt < 2; ++tt) {
        const int T = 2 * w + tt;
        const int p = 16 * T + bb;            // A-fragment row (permuted gate row)
        const int j = (p & 3) * 64 + (p >> 2); // original row: g*64 + u
#pragma unroll
        for (int s = 0; s < 2; ++s) {
            const float* src = Whh + j * HID + 32 * s + 8 * q;
            bf16x8 hi, lo;
#pragma unroll
            for (int r = 0; r < 8; ++r) {
                float v  = src[r];
                __bf16 h = (__bf16)v;
                hi[r] = h;
                lo[r] = (__bf16)(v - (float)h);
            }
            whh_hi[tt][s] = hi;
            whh_lo[tt][s] = lo;
        }
        {
            bf16x8 hi, lo;
#pragma unroll
            for (int r = 0; r < 8; ++r) {
                int f    = 8 * q + r;
                float v  = (f < F_IN) ? Wih[j * F_IN + f] : 0.0f;
                __bf16 h = (__bf16)v;
                hi[r] = h;
                lo[r] = (__bf16)(v - (float)h);
            }
            wih_hi[tt] = hi;
            wih_lo[tt] = lo;
        }
        const int u = 4 * T + q;              // C-layout unit for this (tt, lane)
#pragma unroll
        for (int r = 0; r < 4; ++r)
            bias[tt][r] = bih[r * 64 + u] + bhh[r * 64 + u];
    }

    const float* xrow = X + (long)(b0 + bb) * T_SEQ * F_IN;

    // per-lane X loader: lane needs X[b][t][8q..8q+7] (f>=18 -> 0); 8B-aligned float2s
    auto loadX = [&](int t, float* dst) {
        const float* p = xrow + t * F_IN + 8 * q;
        if (q < 2) {
#pragma unroll
            for (int r = 0; r < 4; ++r) {
                float2 v = *reinterpret_cast<const float2*>(p + 2 * r);
                dst[2 * r]     = v.x;
                dst[2 * r + 1] = v.y;
            }
        } else if (q == 2) {
            float2 v = *reinterpret_cast<const float2*>(p);
            dst[0] = v.x; dst[1] = v.y;
#pragma unroll
            for (int r = 2; r < 8; ++r) dst[r] = 0.0f;
        } else {
#pragma unroll
            for (int r = 0; r < 8; ++r) dst[r] = 0.0f;
        }
    };

    float xv[8];
    loadX(0, xv);
    __syncthreads();

#pragma unroll 2
    for (int t = 0; t < T_SEQ; ++t) {
        const int cur = t & 1;
        const int nxt = cur ^ 1;

        // X B-fragment (hi/lo split)
        bf16x8 xh, xl;
#pragma unroll
        for (int r = 0; r < 8; ++r) {
            float v  = xv[r];
            __bf16 h = (__bf16)v;
            xh[r] = h;
            xl[r] = (__bf16)(v - (float)h);
        }

        // h B-fragments from LDS (k = 32s + 8q + r  ->  kb = 4s + q)
        const bf16x8 bh0 = *reinterpret_cast<const bf16x8*>(&hbuf[cur][0][q][bb][0]);
        const bf16x8 bl0 = *reinterpret_cast<const bf16x8*>(&hbuf[cur][1][q][bb][0]);
        const bf16x8 bh1 = *reinterpret_cast<const bf16x8*>(&hbuf[cur][0][4 + q][bb][0]);
        const bf16x8 bl1 = *reinterpret_cast<const bf16x8*>(&hbuf[cur][1][4 + q][bb][0]);

        // prefetch next timestep's X (latency hidden under MFMA + gate math)
        float xnv[8];
        {
            const int tn = (t + 1 < T_SEQ) ? t + 1 : t;
            loadX(tn, xnv);
        }

        f32x4 acc0 = {bias[0][0], bias[0][1], bias[0][2], bias[0][3]};
        f32x4 acc1 = {bias[1][0], bias[1][1], bias[1][2], bias[1][3]};

        // input projection: 3-product split (hi*hi + lo*hi + hi*lo)
        acc0 = __builtin_amdgcn_mfma_f32_16x16x32_bf16(wih_hi[0], xh, acc0, 0, 0, 0);
        acc1 = __builtin_amdgcn_mfma_f32_16x16x32_bf16(wih_hi[1], xh, acc1, 0, 0, 0);
        acc0 = __builtin_amdgcn_mfma_f32_16x16x32_bf16(wih_lo[0], xh, acc0, 0, 0, 0);
        acc1 = __builtin_amdgcn_mfma_f32_16x16x32_bf16(wih_lo[1], xh, acc1, 0, 0, 0);
        acc0 = __builtin_amdgcn_mfma_f32_16x16x32_bf16(wih_hi[0], xl, acc0, 0, 0, 0);
        acc1 = __builtin_amdgcn_mfma_f32_16x16x32_bf16(wih_hi[1], xl, acc1, 0, 0, 0);

        // recurrent part, K = 64 as two K=32 sub-steps, 3-product split each
        acc0 = __builtin_amdgcn_mfma_f32_16x16x32_bf16(whh_hi[0][0], bh0, acc0, 0, 0, 0);
        acc1 = __builtin_amdgcn_mfma_f32_16x16x32_bf16(whh_hi[1][0], bh0, acc1, 0, 0, 0);
        acc0 = __builtin_amdgcn_mfma_f32_16x16x32_bf16(whh_lo[0][0], bh0, acc0, 0, 0, 0);
        acc1 = __builtin_amdgcn_mfma_f32_16x16x32_bf16(whh_lo[1][0], bh0, acc1, 0, 0, 0);
        acc0 = __builtin_amdgcn_mfma_f32_16x16x32_bf16(whh_hi[0][0], bl0, acc0, 0, 0, 0);
        acc1 = __builtin_amdgcn_mfma_f32_16x16x32_bf16(whh_hi[1][0], bl0, acc1, 0, 0, 0);
        acc0 = __builtin_amdgcn_mfma_f32_16x16x32_bf16(whh_hi[0][1], bh1, acc0, 0, 0, 0);
        acc1 = __builtin_amdgcn_mfma_f32_16x16x32_bf16(whh_hi[1][1], bh1, acc1, 0, 0, 0);
        acc0 = __builtin_amdgcn_mfma_f32_16x16x32_bf16(whh_lo[0][1], bh1, acc0, 0, 0, 0);
        acc1 = __builtin_amdgcn_mfma_f32_16x16x32_bf16(whh_lo[1][1], bh1, acc1, 0, 0, 0);
        acc0 = __builtin_amdgcn_mfma_f32_16x16x32_bf16(whh_hi[0][1], bl1, acc0, 0, 0, 0);
        acc1 = __builtin_amdgcn_mfma_f32_16x16x32_bf16(whh_hi[1][1], bl1, acc1, 0, 0, 0);

        // lane-local cell update: reg r = gate {i,f,g,o} of (bb, u)
#pragma unroll
        for (int tt = 0; tt < 2; ++tt) {
            const f32x4 a = tt ? acc1 : acc0;
            const float gi = sigm(a[0]);
            const float gf = sigm(a[1]);
            const float gg = tanhf_fast(a[2]);
            const float go = sigm(a[3]);
            const float c  = gf * cst[tt] + gi * gg;
            cst[tt] = c;
            const float h = go * tanhf_fast(c);
            const int  u  = 8 * w + 4 * tt + q;
            const __bf16 hh = (__bf16)h;
            const __bf16 hl = (__bf16)(h - (float)hh);
            hbuf[nxt][0][u >> 3][bb][u & 7] = hh;
            hbuf[nxt][1][u >> 3][bb][u & 7] = hl;
            if (t == T_SEQ - 1) h32[bb][u] = h;
        }

#pragma unroll
        for (int r = 0; r < 8; ++r) xv[r] = xnv[r];

        __syncthreads();
    }

    // ---- classifier epilogue: out[b][o] = h . Wcls[o] + bcls[o] ----
    if (tid < NB * NO) {
        const int bo = tid / NO;
        const int o  = tid % NO;
        float s = bcls[o];
#pragma unroll 8
        for (int k = 0; k < HID; ++k)
            s += h32[bo][k] * Wcls[o * HID + k];
        out[(long)(b0 + bo) * NO + o] = s;
    }
}

extern "C" void kernel_launch(void* const* d_in, const int* in_sizes, int n_in,
                              void* d_out, int out_size, void* d_ws, size_t ws_size,
                              hipStream_t stream)
{
    const float* X    = (const float*)d_in[0];
    const float* Wih  = (const float*)d_in[1];
    const float* Whh  = (const float*)d_in[2];
    const float* bih  = (const float*)d_in[3];
    const float* bhh  = (const float*)d_in[4];
    const float* Wcls = (const float*)d_in[5];
    const float* bcls = (const float*)d_in[6];
    float* outp = (float*)d_out;

    dim3 grid(4096 / NB);   // 256 blocks -> 1 per CU
    dim3 block(512);        // 8 waves
    lstm_fused<<<grid, block, 0, stream>>>(X, Wih, Whh, bih, bhh, Wcls, bcls, outp);
}

// Round 8
// 316.874 us; speedup vs baseline: 1.5370x; 1.5370x over previous
//
#include <hip/hip_runtime.h>
#include <hip/hip_bf16.h>

typedef __attribute__((ext_vector_type(8))) __bf16 bf16x8;
typedef __attribute__((ext_vector_type(4))) float  f32x4;

#define T_SEQ 256
#define F_IN  18
#define HID   64
#define NB    16
#define NO    15
#define HPAD  72   // padded LDS row (64 + 8) to spread banks

static __device__ __forceinline__ float rcp_fast(float x) {
    return __builtin_amdgcn_rcpf(x);
}
static __device__ __forceinline__ float sigm(float x) {
    return rcp_fast(1.0f + __expf(-x));
}
static __device__ __forceinline__ float tanh_fast(float x) {
    // 1 - 2/(e^{2x}+1); saturates correctly for |x| large
    return 1.0f - 2.0f * rcp_fast(__expf(2.0f * x) + 1.0f);
}

// 256 blocks x 1024 threads (16 waves). Block owns 16 batches; wave w owns
// gate-row tile T=w of the permuted gate matrix (rows p = 4u+g), i.e. units
// u = 4w..4w+3. Per lane: bb = l&15 (batch col), q = l>>4 (k-group).
// C layout (m89-verified): col=lane&15=bb, row=4q+r -> p = 16w+4q+r ->
// u = 4w+q, gate g = r. One lane-local cell update per lane per step.
//
// K-packing (split-precision 3-product at MFMA rate). Segment maps MUST agree
// between A and B sides (R2 bug: they didn't):
//   input proj (K=64, 2 MFMAs):
//     A = [Wih_hi(18) | Wih_lo(18) | Wih_hi(18) | 0..]
//     B = [x_hi(18)   | x_hi(18)   | x_lo(18)   | 0..]
//     -> Whi.xhi + Wlo.xhi + Whi.xlo
//   recurrent (K=192 as 6 MFMAs): [Whi.hhi(64) | Wlo.hhi(64) | Whi.hlo(64)]
//     (A regs reused for seg0/seg2, B regs reused for seg0/seg1)
__global__ __launch_bounds__(1024, 4) void lstm_fused(
    const float* __restrict__ X,
    const float* __restrict__ Wih,
    const float* __restrict__ Whh,
    const float* __restrict__ bih,
    const float* __restrict__ bhh,
    const float* __restrict__ Wcls,
    const float* __restrict__ bcls,
    float* __restrict__ out)
{
    const int tid = threadIdx.x;
    const int l   = tid & 63;
    const int w   = tid >> 6;   // wave id = row-tile T
    const int q   = l >> 4;     // k-group
    const int bb  = l & 15;     // batch within block
    const int b0  = blockIdx.x * NB;

    // [dbuf][part hi/lo][bb][k padded]
    __shared__ __align__(16) __bf16 hbuf[2][2][NB][HPAD];
    // [dbuf][bb][kpacked padded], kpacked = [x_hi(18)|x_hi(18)|x_lo(18)|0..]
    __shared__ __align__(16) __bf16 xbuf[2][NB][HPAD];
    __shared__ float h32[NB][HID];

    // ---- x staging map: thread -> (batch=w, kpacked=l) ----
    // segments: [0,18): hi  [18,36): hi  [36,54): lo  [54,64): zero
    const int k_s = l;
    int f_s, part_s;                 // part: 0=hi, 1=lo, 2=zero
    if (k_s < 18)      { f_s = k_s;      part_s = 0; }
    else if (k_s < 36) { f_s = k_s - 18; part_s = 0; }
    else if (k_s < 54) { f_s = k_s - 36; part_s = 1; }
    else               { f_s = 0;        part_s = 2; }
    const float* xsrc = X + ((long)(b0 + w) * T_SEQ) * F_IN + f_s;

    // ---- zero initial h (t=0 reads hbuf[0]) ----
    {
        __bf16* hz = &hbuf[0][0][0][0];
        for (int i = tid; i < 2 * NB * HPAD; i += 1024) hz[i] = (__bf16)0.0f;
    }
    // ---- stage x for t=0 ----
    {
        float v = (part_s == 2) ? 0.0f : xsrc[0];
        __bf16 hi = (__bf16)v;
        xbuf[0][w][k_s] = (part_s == 1) ? (__bf16)(v - (float)hi) : hi;
    }

    // ---- constant A-fragments (live whole kernel) ----
    bf16x8 whh_hi[2], whh_lo[2], wih[2];
    {
        const int prow = 16 * w + bb;              // permuted gate row
        const int jrow = (prow & 3) * 64 + (prow >> 2); // original row g*64+u
#pragma unroll
        for (int kk = 0; kk < 2; ++kk) {
            bf16x8 hi, lo, xa;
#pragma unroll
            for (int r = 0; r < 8; ++r) {
                const int k = 32 * kk + 8 * q + r;
                const float v = Whh[jrow * HID + k];
                const __bf16 vh = (__bf16)v;
                hi[r] = vh;
                lo[r] = (__bf16)(v - (float)vh);
                // A-side packed map: [0,18): Wih_hi  [18,36): Wih_lo
                //                    [36,54): Wih_hi [54,64): zero
                int f, part;
                if (k < 18)      { f = k;      part = 0; }
                else if (k < 36) { f = k - 18; part = 1; }
                else if (k < 54) { f = k - 36; part = 0; }
                else             { f = 0;      part = 2; }
                const float wv = (part == 2) ? 0.0f : Wih[jrow * F_IN + f];
                const __bf16 wh = (__bf16)wv;
                xa[r] = (part == 1) ? (__bf16)(wv - (float)wh) : wh;
            }
            whh_hi[kk] = hi;
            whh_lo[kk] = lo;
            wih[kk]    = xa;
        }
    }

    const int u_c = 4 * w + q;                    // this lane's hidden unit
    float bias4[4];
#pragma unroll
    for (int r = 0; r < 4; ++r) bias4[r] = bih[r * 64 + u_c] + bhh[r * 64 + u_c];

    __syncthreads();

    float cst = 0.0f;

#pragma unroll 2
    for (int t = 0; t < T_SEQ; ++t) {
        const int cur = t & 1;
        const int nxt = cur ^ 1;

        // issue next-step x load early (latency hides under MFMA chain)
        const int tn = (t + 1 < T_SEQ) ? (t + 1) : (T_SEQ - 1);
        const float vstage = (part_s == 2) ? 0.0f : xsrc[tn * F_IN];

        // B-fragments from LDS (contiguous 16B per lane)
        const bf16x8 bx0 = *reinterpret_cast<const bf16x8*>(&xbuf[cur][bb][8 * q]);
        const bf16x8 bx1 = *reinterpret_cast<const bf16x8*>(&xbuf[cur][bb][32 + 8 * q]);
        const bf16x8 bh0 = *reinterpret_cast<const bf16x8*>(&hbuf[cur][0][bb][8 * q]);
        const bf16x8 bh1 = *reinterpret_cast<const bf16x8*>(&hbuf[cur][0][bb][32 + 8 * q]);
        const bf16x8 bl0 = *reinterpret_cast<const bf16x8*>(&hbuf[cur][1][bb][8 * q]);
        const bf16x8 bl1 = *reinterpret_cast<const bf16x8*>(&hbuf[cur][1][bb][32 + 8 * q]);

        f32x4 acc = {bias4[0], bias4[1], bias4[2], bias4[3]};
        // input projection (split packed in K)
        acc = __builtin_amdgcn_mfma_f32_16x16x32_bf16(wih[0],    bx0, acc, 0, 0, 0);
        acc = __builtin_amdgcn_mfma_f32_16x16x32_bf16(wih[1],    bx1, acc, 0, 0, 0);
        // recurrent: Whi.h_hi + Wlo.h_hi + Whi.h_lo
        acc = __builtin_amdgcn_mfma_f32_16x16x32_bf16(whh_hi[0], bh0, acc, 0, 0, 0);
        acc = __builtin_amdgcn_mfma_f32_16x16x32_bf16(whh_hi[1], bh1, acc, 0, 0, 0);
        acc = __builtin_amdgcn_mfma_f32_16x16x32_bf16(whh_lo[0], bh0, acc, 0, 0, 0);
        acc = __builtin_amdgcn_mfma_f32_16x16x32_bf16(whh_lo[1], bh1, acc, 0, 0, 0);
        acc = __builtin_amdgcn_mfma_f32_16x16x32_bf16(whh_hi[0], bl0, acc, 0, 0, 0);
        acc = __builtin_amdgcn_mfma_f32_16x16x32_bf16(whh_hi[1], bl1, acc, 0, 0, 0);

        // write next-step x into the other buffer (read last iter, safe)
        {
            const __bf16 sh = (__bf16)vstage;
            xbuf[nxt][w][k_s] = (part_s == 1) ? (__bf16)(vstage - (float)sh) : sh;
        }

        // lane-local cell update: acc[r] = gate {i,f,g,o} of (bb, u_c)
        const float gi = sigm(acc[0]);
        const float gf = sigm(acc[1]);
        const float gg = tanh_fast(acc[2]);
        const float go = sigm(acc[3]);
        const float c  = gf * cst + gi * gg;
        cst = c;
        const float h  = go * tanh_fast(c);
        const __bf16 hh = (__bf16)h;
        const __bf16 hl = (__bf16)(h - (float)hh);
        hbuf[nxt][0][bb][u_c] = hh;
        hbuf[nxt][1][bb][u_c] = hl;
        if (t == T_SEQ - 1) h32[bb][u_c] = h;

        __syncthreads();
    }

    // ---- classifier epilogue: out[b][o] = h . Wcls[o] + bcls[o] ----
    if (tid < NB * NO) {
        const int bo = tid / NO;
        const int o  = tid % NO;
        float s = bcls[o];
#pragma unroll 8
        for (int k = 0; k < HID; ++k)
            s += h32[bo][k] * Wcls[o * HID + k];
        out[(long)(b0 + bo) * NO + o] = s;
    }
}

extern "C" void kernel_launch(void* const* d_in, const int* in_sizes, int n_in,
                              void* d_out, int out_size, void* d_ws, size_t ws_size,
                              hipStream_t stream)
{
    const float* X    = (const float*)d_in[0];
    const float* Wih  = (const float*)d_in[1];
    const float* Whh  = (const float*)d_in[2];
    const float* bih  = (const float*)d_in[3];
    const float* bhh  = (const float*)d_in[4];
    const float* Wcls = (const float*)d_in[5];
    const float* bcls = (const float*)d_in[6];
    float* outp = (float*)d_out;

    dim3 grid(4096 / NB);   // 256 blocks -> 1 per CU
    dim3 block(1024);       // 16 waves -> 4 waves/SIMD
    lstm_fused<<<grid, block, 0, stream>>>(X, Wih, Whh, bih, bhh, Wcls, bcls, outp);
}